// Round 8
// baseline (756.554 us; speedup 1.0000x reference)
//
#include <hip/hip_runtime.h>
#include <math.h>

// CollapseEngine R8: R6 kernel (bf16 W-hi x (Bh+Bl), phi-permuted, counted-vmcnt
// pipeline) + ISOLATED T5: s_setprio(1) around each 16-MFMA cluster.
// Everything else bit-identical to R6 (747 us, absmax 0.0234, VGPR 128).
// phi(ks,G,i) = 32*ks + 16*(i>>2) + 4*G + (i&3),  G = lane>>4.

#define DIMX 256
#define NL 6
#define CPAD 68   // padded float stride for per-G const arrays

typedef float f32x4 __attribute__((ext_vector_type(4)));
typedef short short8 __attribute__((ext_vector_type(8)));
typedef unsigned int u32x4 __attribute__((ext_vector_type(4)));

// 16 chunks of 1024 granules (16KB); chunk c = (g*2+pass)*4 + kk, kk=ks>>1
#define CHB(c) ((c) * 1024)

// pack f32 pair -> (hi u32 = 2 bf16 trunc, lo u32 = 2 bf16 residual)
#define PACKPAIR(X0, X1, HI, LO)                                                 \
    {                                                                            \
        unsigned b0_ = __float_as_uint(X0), b1_ = __float_as_uint(X1);           \
        HI = __builtin_amdgcn_perm(b1_, b0_, 0x07060302u);                       \
        float l0_ = (X0) - __uint_as_float(b0_ & 0xffff0000u);                   \
        float l1_ = (X1) - __uint_as_float(b1_ & 0xffff0000u);                   \
        asm("v_cvt_pk_bf16_f32 %0, %1, %2" : "=v"(LO) : "v"(l0_), "v"(l1_));     \
    }

// A = W-hi only; B = hi + lo
#define MMAC2(ACC, Ah, Bh, Bl)                                                   \
    ACC = __builtin_amdgcn_mfma_f32_16x16x32_bf16(Ah, Bh, ACC, 0, 0, 0);         \
    ACC = __builtin_amdgcn_mfma_f32_16x16x32_bf16(Ah, Bl, ACC, 0, 0, 0);

// ---------------- W hi-frag precompute (phi-ordered) ----------------
// granule gi = [g(2)][pass(2)][kk(4)][ks2(2)][t8(8)][lane(64)] = 16384 x 16B
// lane ln holds A[m = 16*(pass*8+t8) + (ln&15)][slots (G=ln>>4)*8 + 0..7]
// for ks = kk*2+ks2; slot i carries bf16_trunc(W[m][phi(ks,G,i)]).
__global__ void wsplit(const float* __restrict__ W1, const float* __restrict__ W2,
                       u32x4* __restrict__ ws) {
    int gi   = blockIdx.x * 256 + threadIdx.x;      // 0..16383
    int ln   = gi & 63;
    int t8   = (gi >> 6) & 7;
    int ks2  = (gi >> 9) & 1;
    int kk   = (gi >> 10) & 3;
    int pass = (gi >> 12) & 1;
    int g    = (gi >> 13) & 1;
    int ks   = kk * 2 + ks2;
    int m    = (pass * 8 + t8) * 16 + (ln & 15);
    int G    = ln >> 4;
    const float* Wg = g ? W2 : W1;
    unsigned o[4];
#pragma unroll
    for (int p = 0; p < 4; ++p) {
        int f = 32 * ks + ((p >> 1) << 4) + 4 * G + ((p & 1) << 1);
        unsigned b0 = __float_as_uint(Wg[m * DIMX + f]);
        unsigned b1 = __float_as_uint(Wg[m * DIMX + f + 1]);
        o[p] = __builtin_amdgcn_perm(b1, b0, 0x07060302u);
    }
    u32x4 out = {o[0], o[1], o[2], o[3]};
    ws[gi] = out;
}

// ---------------- main fused kernel ----------------

// stage one 16KB chunk (1024 granules): 512 thr x 2 x 16B
#define STAGE(gIdxBase, ldsSlotBase)                                             \
    {                                                                            \
        _Pragma("unroll")                                                        \
        for (int i_ = 0; i_ < 2; ++i_) {                                         \
            const int off_ = ((w * 2 + i_) << 6);                                \
            __builtin_amdgcn_global_load_lds(                                    \
                (const __attribute__((address_space(1))) void*)(ws + (gIdxBase) + off_ + lane), \
                (__attribute__((address_space(3))) void*)(&wf[(ldsSlotBase) + off_]),           \
                16, 0, 0);                                                       \
        }                                                                        \
    }

// counted-vmcnt pipeline barrier: own chunk's 2 loads complete, the 2
// prefetched chunks (4 loads) stay in flight. Raw barrier, no drain.
#define PIPE_SYNC()                                                              \
    {                                                                            \
        asm volatile("s_waitcnt vmcnt(4)" ::: "memory");                         \
        __builtin_amdgcn_sched_barrier(0);                                       \
        __builtin_amdgcn_s_barrier();                                            \
        __builtin_amdgcn_sched_barrier(0);                                       \
    }

__global__ __launch_bounds__(512, 2)
void collapse_mfma16(const float* __restrict__ h0,
                     const float* __restrict__ b1f,
                     const float* __restrict__ b2f,
                     const float* __restrict__ anchors,
                     const u32x4* __restrict__ ws,
                     float* __restrict__ out_h,
                     float* __restrict__ out_align,
                     float* __restrict__ out_div,
                     float* __restrict__ out_tens,
                     int B)
{
    __shared__ __align__(16) u32x4 wf[4096];         // 4 x 16KB W-frag buffers
    __shared__ __align__(16) float an_reg[3][272];   // padded (stride CPAD=68)
    __shared__ __align__(16) float b1_reg[272];
    __shared__ __align__(16) float b2_reg[272];
    __shared__ float an_inv[3];

    const int tid  = threadIdx.x;
    const int w    = tid >> 6;
    const int lane = tid & 63;
    const int G    = lane >> 4;          // k-octet / D-row group
    const int c    = lane & 15;          // batch col within wave tile
    const int bglob = blockIdx.x * 128 + w * 16 + c;

    // anchor inverse norms (waves 0..2)
    if (w < 3) {
        const float4 av = *(const float4*)&anchors[w * DIMX + lane * 4];
        float ss = av.x * av.x + av.y * av.y + av.z * av.z + av.w * av.w;
#pragma unroll
        for (int m = 1; m < 64; m <<= 1) ss += __shfl_xor(ss, m, 64);
        if (lane == 0) an_inv[w] = 1.0f / fmaxf(sqrtf(ss), 1e-12f);
    }
    __syncthreads();

    // const arrays in phi-layout, padded: idx = Gc*CPAD + s,
    // feat f = 16*(s>>2) + 4*Gc + (s&3)
    {
        int idx = tid & 255;
        int Gc = idx >> 6, s = idx & 63;
        int f = 16 * (s >> 2) + 4 * Gc + (s & 3);
        int pidx = Gc * CPAD + s;
        if (tid < 256) {
            b1_reg[pidx] = b1f[f];
            b2_reg[pidx] = b2f[f];
        } else {
#pragma unroll
            for (int k = 0; k < 3; ++k)
                an_reg[k][pidx] = anchors[k * DIMX + f] * an_inv[k];
        }
    }
    __syncthreads();

    // load h0 into phi-layout regs: hr[mt*4+r] = h0[row][16mt+4G+r]
    float hr[64];
#pragma unroll
    for (int mt = 0; mt < 16; ++mt) {
        const float4 v = *(const float4*)&h0[(size_t)bglob * DIMX + 16 * mt + 4 * G];
        hr[mt * 4 + 0] = v.x; hr[mt * 4 + 1] = v.y;
        hr[mt * 4 + 2] = v.z; hr[mt * 4 + 3] = v.w;
    }

    // pipeline prologue: prefetch chunks 0,1,2 into bufs 0,1,2
    STAGE(CHB(0), 0);
    STAGE(CHB(1), 1024);
    STAGE(CHB(2), 2048);

#pragma unroll 1
    for (int layer = 0; layer < NL; ++layer) {
        // ---------- stats: p0=|h|^2, dk=h.Ak ; |h-Ak|^2 = p0-2dk+1 ----------
        float p0 = 0, d0 = 0, d1 = 0, d2 = 0;
#pragma unroll
        for (int q = 0; q < 16; ++q) {
            const float4 a0 = *(const float4*)&an_reg[0][G * CPAD + q * 4];
            const float4 a1 = *(const float4*)&an_reg[1][G * CPAD + q * 4];
            const float4 a2 = *(const float4*)&an_reg[2][G * CPAD + q * 4];
            float x;
            x = hr[q*4+0]; p0 += x*x; d0 += x*a0.x; d1 += x*a1.x; d2 += x*a2.x;
            x = hr[q*4+1]; p0 += x*x; d0 += x*a0.y; d1 += x*a1.y; d2 += x*a2.y;
            x = hr[q*4+2]; p0 += x*x; d0 += x*a0.z; d1 += x*a1.z; d2 += x*a2.z;
            x = hr[q*4+3]; p0 += x*x; d0 += x*a0.w; d1 += x*a1.w; d2 += x*a2.w;
        }
        p0 += __shfl_xor(p0, 16); d0 += __shfl_xor(d0, 16);
        d1 += __shfl_xor(d1, 16); d2 += __shfl_xor(d2, 16);
        p0 += __shfl_xor(p0, 32); d0 += __shfl_xor(d0, 32);
        d1 += __shfl_xor(d1, 32); d2 += __shfl_xor(d2, 32);
        const float inv_rn = 1.0f / fmaxf(sqrtf(p0), 1e-12f);
        const float al0 = d0 * inv_rn, al1 = d1 * inv_rn, al2 = d2 * inv_rn;
        const float dv0 = 1.0f - al0, dv1 = 1.0f - al1, dv2 = 1.0f - al2;
        const float c0 = -0.10f * dv0 / fmaxf(sqrtf(fmaxf(p0 - 2.0f*d0 + 1.0f, 0.0f)), 1e-12f);
        const float c1 = -0.10f * dv1 / fmaxf(sqrtf(fmaxf(p0 - 2.0f*d1 + 1.0f, 0.0f)), 1e-12f);
        const float c2 = -0.05f * dv2 / fmaxf(sqrtf(fmaxf(p0 - 2.0f*d2 + 1.0f, 0.0f)), 1e-12f);
        if (G == 0) {
            const long long tb = ((long long)layer * B + bglob) * 3;
            out_align[tb+0] = al0; out_align[tb+1] = al1; out_align[tb+2] = al2;
            out_div[tb+0] = dv0;   out_div[tb+1] = dv1;   out_div[tb+2] = dv2;
            out_tens[tb+0] = dv0*dv0; out_tens[tb+1] = dv1*dv1; out_tens[tb+2] = dv2*dv2;
        }

        // ---------- G1: t = tanh(W1 h + b1); windows = (pass, kk) ----------
        unsigned tph[32], tpl[32];
#pragma unroll
        for (int pass = 0; pass < 2; ++pass) {
            f32x4 ac[8];
#pragma unroll
            for (int j = 0; j < 8; ++j) ac[j] = (f32x4)(0.0f);
#pragma unroll
            for (int kk = 0; kk < 4; ++kk) {
                const int s = pass * 4 + kk;
                PIPE_SYNC();
                STAGE(CHB((s + 3) & 15), ((s + 3) & 3) * 1024);
                const int cb = (s & 3) * 1024;
#pragma unroll
                for (int ks2 = 0; ks2 < 2; ++ks2) {
                    const int ks = kk * 2 + ks2;
                    unsigned bh[4], bl[4];
#pragma unroll
                    for (int p = 0; p < 4; ++p)
                        PACKPAIR(hr[8*ks + 2*p], hr[8*ks + 2*p + 1], bh[p], bl[p]);
                    u32x4 thi = {bh[0], bh[1], bh[2], bh[3]};
                    u32x4 tlo = {bl[0], bl[1], bl[2], bl[3]};
                    const short8 Bh = __builtin_bit_cast(short8, thi);
                    const short8 Bl = __builtin_bit_cast(short8, tlo);
                    __builtin_amdgcn_s_setprio(1);
#pragma unroll
                    for (int j = 0; j < 8; ++j) {
                        const short8 Ah = __builtin_bit_cast(short8,
                            wf[cb + ks2*512 + j*64 + lane]);
                        MMAC2(ac[j], Ah, Bh, Bl);
                    }
                    __builtin_amdgcn_s_setprio(0);
                }
            }
            // tanh + b1, pack into t (phi-layout)
#pragma unroll
            for (int j = 0; j < 8; ++j) {
                const int mt = pass * 8 + j;
                const float4 bq = *(const float4*)&b1_reg[G * CPAD + mt * 4];
                float tv[4];
#pragma unroll
                for (int r = 0; r < 4; ++r) {
                    float x = ac[j][r] + ((r==0)?bq.x:(r==1)?bq.y:(r==2)?bq.z:bq.w);
                    float e = __expf(2.0f * x);
                    tv[r] = 1.0f - 2.0f * __builtin_amdgcn_rcpf(e + 1.0f);
                }
                const int ti = 4 * (mt >> 1) + 2 * (mt & 1);
                PACKPAIR(tv[0], tv[1], tph[ti],     tpl[ti]);
                PACKPAIR(tv[2], tv[3], tph[ti + 1], tpl[ti + 1]);
            }
        }

        // ---------- G2: h' = (h + b2 + force) + W2 t ----------
        const float csum = 1.0f + c0 + c1 + c2;
#pragma unroll
        for (int pass = 0; pass < 2; ++pass) {
            f32x4 ac[8];
#pragma unroll
            for (int j = 0; j < 8; ++j) {
                const int mt = pass * 8 + j;
                const float4 a0 = *(const float4*)&an_reg[0][G * CPAD + mt * 4];
                const float4 a1 = *(const float4*)&an_reg[1][G * CPAD + mt * 4];
                const float4 a2 = *(const float4*)&an_reg[2][G * CPAD + mt * 4];
                const float4 bq = *(const float4*)&b2_reg[G * CPAD + mt * 4];
                ac[j][0] = hr[mt*4+0]*csum - (c0*a0.x + c1*a1.x + c2*a2.x) + bq.x;
                ac[j][1] = hr[mt*4+1]*csum - (c0*a0.y + c1*a1.y + c2*a2.y) + bq.y;
                ac[j][2] = hr[mt*4+2]*csum - (c0*a0.z + c1*a1.z + c2*a2.z) + bq.z;
                ac[j][3] = hr[mt*4+3]*csum - (c0*a0.w + c1*a1.w + c2*a2.w) + bq.w;
            }
#pragma unroll
            for (int kk = 0; kk < 4; ++kk) {
                const int s = 8 + pass * 4 + kk;
                PIPE_SYNC();
                STAGE(CHB((s + 3) & 15), ((s + 3) & 3) * 1024);
                const int cb = (s & 3) * 1024;
#pragma unroll
                for (int ks2 = 0; ks2 < 2; ++ks2) {
                    const int ks = kk * 2 + ks2;
                    u32x4 thi = {tph[4*ks+0], tph[4*ks+1], tph[4*ks+2], tph[4*ks+3]};
                    u32x4 tlo = {tpl[4*ks+0], tpl[4*ks+1], tpl[4*ks+2], tpl[4*ks+3]};
                    const short8 Bh = __builtin_bit_cast(short8, thi);
                    const short8 Bl = __builtin_bit_cast(short8, tlo);
                    __builtin_amdgcn_s_setprio(1);
#pragma unroll
                    for (int j = 0; j < 8; ++j) {
                        const short8 Ah = __builtin_bit_cast(short8,
                            wf[cb + ks2*512 + j*64 + lane]);
                        MMAC2(ac[j], Ah, Bh, Bl);
                    }
                    __builtin_amdgcn_s_setprio(0);
                }
            }
#pragma unroll
            for (int j = 0; j < 8; ++j) {
                const int mt = pass * 8 + j;
                hr[mt*4+0] = ac[j][0]; hr[mt*4+1] = ac[j][1];
                hr[mt*4+2] = ac[j][2]; hr[mt*4+3] = ac[j][3];
            }
        }

        // ---------- norm clip (in regs) ----------
        {
            float ss = 0.0f;
#pragma unroll
            for (int s = 0; s < 64; ++s) ss += hr[s] * hr[s];
            ss += __shfl_xor(ss, 16);
            ss += __shfl_xor(ss, 32);
            const float n = sqrtf(ss);
            const float sc = (n > 10.0f) ? (10.0f / (n + 1e-8f)) : 1.0f;
#pragma unroll
            for (int s = 0; s < 64; ++s) hr[s] *= sc;
        }
    }

    // ---------- store h_final ----------
#pragma unroll
    for (int mt = 0; mt < 16; ++mt) {
        float4 v;
        v.x = hr[mt*4+0]; v.y = hr[mt*4+1]; v.z = hr[mt*4+2]; v.w = hr[mt*4+3];
        *(float4*)&out_h[(size_t)bglob * DIMX + 16 * mt + 4 * G] = v;
    }
}

extern "C" void kernel_launch(void* const* d_in, const int* in_sizes, int n_in,
                              void* d_out, int out_size, void* d_ws, size_t ws_size,
                              hipStream_t stream) {
    const float* h0      = (const float*)d_in[0];
    const float* W1      = (const float*)d_in[1];
    const float* b1      = (const float*)d_in[2];
    const float* W2      = (const float*)d_in[3];
    const float* b2      = (const float*)d_in[4];
    const float* anchors = (const float*)d_in[5];
    const int B = in_sizes[0] / DIMX;

    float* out_h     = (float*)d_out;
    float* out_align = out_h + (long long)B * DIMX;
    float* out_div   = out_align + (long long)NL * B * 3;
    float* out_tens  = out_div   + (long long)NL * B * 3;

    u32x4* ws = (u32x4*)d_ws;   // 256 KiB

    hipLaunchKernelGGL(wsplit, dim3(64), dim3(256), 0, stream, W1, W2, ws);
    hipLaunchKernelGGL(collapse_mfma16, dim3(B / 128), dim3(512), 0, stream,
                       h0, b1, b2, anchors, ws,
                       out_h, out_align, out_div, out_tens, B);
}

// Round 9
// 545.057 us; speedup vs baseline: 1.3880x; 1.3880x over previous
//
#include <hip/hip_runtime.h>
#include <math.h>

// CollapseEngine R9: pure-RNE bf16 MFMA. From R6/R8 base:
//  - A (W) hi: trunc -> RNE (v_cvt_pk_bf16_f32) in wsplit
//  - B (h, t): drop lo term entirely; single RNE bf16 pack
//  - MFMAs halve (256/layer/wave), B-pack VALU 4x cheaper, tpl freed
//  - setprio removed (R8 measured null)
// Counted-vmcnt pipeline, phi-permuted layout unchanged.
// phi(ks,G,i) = 32*ks + 16*(i>>2) + 4*G + (i&3),  G = lane>>4.

#define DIMX 256
#define NL 6
#define CPAD 68   // padded float stride for per-G const arrays

typedef float f32x4 __attribute__((ext_vector_type(4)));
typedef short short8 __attribute__((ext_vector_type(8)));
typedef unsigned int u32x4 __attribute__((ext_vector_type(4)));

// 16 chunks of 1024 granules (16KB); chunk c = (g*2+pass)*4 + kk, kk=ks>>1
#define CHB(c) ((c) * 1024)

// RNE-pack f32 pair -> u32 of 2 bf16 (lo = X0, hi = X1)
#define PACKB(X0, X1, DST)                                                       \
    asm("v_cvt_pk_bf16_f32 %0, %1, %2" : "=v"(DST) : "v"(X0), "v"(X1));

// ---------------- W RNE-bf16 frag precompute (phi-ordered) ----------------
// granule gi = [g(2)][pass(2)][kk(4)][ks2(2)][t8(8)][lane(64)] = 16384 x 16B
// lane ln holds A[m = 16*(pass*8+t8) + (ln&15)][slots (G=ln>>4)*8 + 0..7]
// for ks = kk*2+ks2; slot i carries bf16_rne(W[m][phi(ks,G,i)]).
__global__ void wsplit(const float* __restrict__ W1, const float* __restrict__ W2,
                       u32x4* __restrict__ ws) {
    int gi   = blockIdx.x * 256 + threadIdx.x;      // 0..16383
    int ln   = gi & 63;
    int t8   = (gi >> 6) & 7;
    int ks2  = (gi >> 9) & 1;
    int kk   = (gi >> 10) & 3;
    int pass = (gi >> 12) & 1;
    int g    = (gi >> 13) & 1;
    int ks   = kk * 2 + ks2;
    int m    = (pass * 8 + t8) * 16 + (ln & 15);
    int G    = ln >> 4;
    const float* Wg = g ? W2 : W1;
    unsigned o[4];
#pragma unroll
    for (int p = 0; p < 4; ++p) {
        int f = 32 * ks + ((p >> 1) << 4) + 4 * G + ((p & 1) << 1);
        float x0 = Wg[m * DIMX + f];
        float x1 = Wg[m * DIMX + f + 1];
        unsigned hp;
        PACKB(x0, x1, hp);
        o[p] = hp;
    }
    u32x4 out = {o[0], o[1], o[2], o[3]};
    ws[gi] = out;
}

// ---------------- main fused kernel ----------------

// stage one 16KB chunk (1024 granules): 512 thr x 2 x 16B
#define STAGE(gIdxBase, ldsSlotBase)                                             \
    {                                                                            \
        _Pragma("unroll")                                                        \
        for (int i_ = 0; i_ < 2; ++i_) {                                         \
            const int off_ = ((w * 2 + i_) << 6);                                \
            __builtin_amdgcn_global_load_lds(                                    \
                (const __attribute__((address_space(1))) void*)(ws + (gIdxBase) + off_ + lane), \
                (__attribute__((address_space(3))) void*)(&wf[(ldsSlotBase) + off_]),           \
                16, 0, 0);                                                       \
        }                                                                        \
    }

// counted-vmcnt pipeline barrier: own chunk's 2 loads complete, the 2
// prefetched chunks (4 loads) stay in flight. Raw barrier, no drain.
#define PIPE_SYNC()                                                              \
    {                                                                            \
        asm volatile("s_waitcnt vmcnt(4)" ::: "memory");                         \
        __builtin_amdgcn_sched_barrier(0);                                       \
        __builtin_amdgcn_s_barrier();                                            \
        __builtin_amdgcn_sched_barrier(0);                                       \
    }

__global__ __launch_bounds__(512, 2)
void collapse_mfma16(const float* __restrict__ h0,
                     const float* __restrict__ b1f,
                     const float* __restrict__ b2f,
                     const float* __restrict__ anchors,
                     const u32x4* __restrict__ ws,
                     float* __restrict__ out_h,
                     float* __restrict__ out_align,
                     float* __restrict__ out_div,
                     float* __restrict__ out_tens,
                     int B)
{
    __shared__ __align__(16) u32x4 wf[4096];         // 4 x 16KB W-frag buffers
    __shared__ __align__(16) float an_reg[3][272];   // padded (stride CPAD=68)
    __shared__ __align__(16) float b1_reg[272];
    __shared__ __align__(16) float b2_reg[272];
    __shared__ float an_inv[3];

    const int tid  = threadIdx.x;
    const int w    = tid >> 6;
    const int lane = tid & 63;
    const int G    = lane >> 4;          // k-octet / D-row group
    const int c    = lane & 15;          // batch col within wave tile
    const int bglob = blockIdx.x * 128 + w * 16 + c;

    // anchor inverse norms (waves 0..2)
    if (w < 3) {
        const float4 av = *(const float4*)&anchors[w * DIMX + lane * 4];
        float ss = av.x * av.x + av.y * av.y + av.z * av.z + av.w * av.w;
#pragma unroll
        for (int m = 1; m < 64; m <<= 1) ss += __shfl_xor(ss, m, 64);
        if (lane == 0) an_inv[w] = 1.0f / fmaxf(sqrtf(ss), 1e-12f);
    }
    __syncthreads();

    // const arrays in phi-layout, padded: idx = Gc*CPAD + s,
    // feat f = 16*(s>>2) + 4*Gc + (s&3)
    {
        int idx = tid & 255;
        int Gc = idx >> 6, s = idx & 63;
        int f = 16 * (s >> 2) + 4 * Gc + (s & 3);
        int pidx = Gc * CPAD + s;
        if (tid < 256) {
            b1_reg[pidx] = b1f[f];
            b2_reg[pidx] = b2f[f];
        } else {
#pragma unroll
            for (int k = 0; k < 3; ++k)
                an_reg[k][pidx] = anchors[k * DIMX + f] * an_inv[k];
        }
    }
    __syncthreads();

    // load h0 into phi-layout regs: hr[mt*4+r] = h0[row][16mt+4G+r]
    float hr[64];
#pragma unroll
    for (int mt = 0; mt < 16; ++mt) {
        const float4 v = *(const float4*)&h0[(size_t)bglob * DIMX + 16 * mt + 4 * G];
        hr[mt * 4 + 0] = v.x; hr[mt * 4 + 1] = v.y;
        hr[mt * 4 + 2] = v.z; hr[mt * 4 + 3] = v.w;
    }

    // pipeline prologue: prefetch chunks 0,1,2 into bufs 0,1,2
    STAGE(CHB(0), 0);
    STAGE(CHB(1), 1024);
    STAGE(CHB(2), 2048);

#pragma unroll 1
    for (int layer = 0; layer < NL; ++layer) {
        // ---------- stats: p0=|h|^2, dk=h.Ak ; |h-Ak|^2 = p0-2dk+1 ----------
        float p0 = 0, d0 = 0, d1 = 0, d2 = 0;
#pragma unroll
        for (int q = 0; q < 16; ++q) {
            const float4 a0 = *(const float4*)&an_reg[0][G * CPAD + q * 4];
            const float4 a1 = *(const float4*)&an_reg[1][G * CPAD + q * 4];
            const float4 a2 = *(const float4*)&an_reg[2][G * CPAD + q * 4];
            float x;
            x = hr[q*4+0]; p0 += x*x; d0 += x*a0.x; d1 += x*a1.x; d2 += x*a2.x;
            x = hr[q*4+1]; p0 += x*x; d0 += x*a0.y; d1 += x*a1.y; d2 += x*a2.y;
            x = hr[q*4+2]; p0 += x*x; d0 += x*a0.z; d1 += x*a1.z; d2 += x*a2.z;
            x = hr[q*4+3]; p0 += x*x; d0 += x*a0.w; d1 += x*a1.w; d2 += x*a2.w;
        }
        p0 += __shfl_xor(p0, 16); d0 += __shfl_xor(d0, 16);
        d1 += __shfl_xor(d1, 16); d2 += __shfl_xor(d2, 16);
        p0 += __shfl_xor(p0, 32); d0 += __shfl_xor(d0, 32);
        d1 += __shfl_xor(d1, 32); d2 += __shfl_xor(d2, 32);
        const float inv_rn = 1.0f / fmaxf(sqrtf(p0), 1e-12f);
        const float al0 = d0 * inv_rn, al1 = d1 * inv_rn, al2 = d2 * inv_rn;
        const float dv0 = 1.0f - al0, dv1 = 1.0f - al1, dv2 = 1.0f - al2;
        const float c0 = -0.10f * dv0 / fmaxf(sqrtf(fmaxf(p0 - 2.0f*d0 + 1.0f, 0.0f)), 1e-12f);
        const float c1 = -0.10f * dv1 / fmaxf(sqrtf(fmaxf(p0 - 2.0f*d1 + 1.0f, 0.0f)), 1e-12f);
        const float c2 = -0.05f * dv2 / fmaxf(sqrtf(fmaxf(p0 - 2.0f*d2 + 1.0f, 0.0f)), 1e-12f);
        if (G == 0) {
            const long long tb = ((long long)layer * B + bglob) * 3;
            out_align[tb+0] = al0; out_align[tb+1] = al1; out_align[tb+2] = al2;
            out_div[tb+0] = dv0;   out_div[tb+1] = dv1;   out_div[tb+2] = dv2;
            out_tens[tb+0] = dv0*dv0; out_tens[tb+1] = dv1*dv1; out_tens[tb+2] = dv2*dv2;
        }

        // ---------- G1: t = tanh(W1 h + b1); windows = (pass, kk) ----------
        unsigned tph[32];
#pragma unroll
        for (int pass = 0; pass < 2; ++pass) {
            f32x4 ac[8];
#pragma unroll
            for (int j = 0; j < 8; ++j) ac[j] = (f32x4)(0.0f);
#pragma unroll
            for (int kk = 0; kk < 4; ++kk) {
                const int s = pass * 4 + kk;
                PIPE_SYNC();
                STAGE(CHB((s + 3) & 15), ((s + 3) & 3) * 1024);
                const int cb = (s & 3) * 1024;
#pragma unroll
                for (int ks2 = 0; ks2 < 2; ++ks2) {
                    const int ks = kk * 2 + ks2;
                    unsigned bh[4];
#pragma unroll
                    for (int p = 0; p < 4; ++p)
                        PACKB(hr[8*ks + 2*p], hr[8*ks + 2*p + 1], bh[p]);
                    u32x4 thi = {bh[0], bh[1], bh[2], bh[3]};
                    const short8 Bh = __builtin_bit_cast(short8, thi);
#pragma unroll
                    for (int j = 0; j < 8; ++j) {
                        const short8 Ah = __builtin_bit_cast(short8,
                            wf[cb + ks2*512 + j*64 + lane]);
                        ac[j] = __builtin_amdgcn_mfma_f32_16x16x32_bf16(Ah, Bh, ac[j], 0, 0, 0);
                    }
                }
            }
            // tanh + b1, pack into t (phi-layout)
#pragma unroll
            for (int j = 0; j < 8; ++j) {
                const int mt = pass * 8 + j;
                const float4 bq = *(const float4*)&b1_reg[G * CPAD + mt * 4];
                float tv[4];
#pragma unroll
                for (int r = 0; r < 4; ++r) {
                    float x = ac[j][r] + ((r==0)?bq.x:(r==1)?bq.y:(r==2)?bq.z:bq.w);
                    float e = __expf(2.0f * x);
                    tv[r] = 1.0f - 2.0f * __builtin_amdgcn_rcpf(e + 1.0f);
                }
                const int ti = 4 * (mt >> 1) + 2 * (mt & 1);
                PACKB(tv[0], tv[1], tph[ti]);
                PACKB(tv[2], tv[3], tph[ti + 1]);
            }
        }

        // ---------- G2: h' = (h + b2 + force) + W2 t ----------
        const float csum = 1.0f + c0 + c1 + c2;
#pragma unroll
        for (int pass = 0; pass < 2; ++pass) {
            f32x4 ac[8];
#pragma unroll
            for (int j = 0; j < 8; ++j) {
                const int mt = pass * 8 + j;
                const float4 a0 = *(const float4*)&an_reg[0][G * CPAD + mt * 4];
                const float4 a1 = *(const float4*)&an_reg[1][G * CPAD + mt * 4];
                const float4 a2 = *(const float4*)&an_reg[2][G * CPAD + mt * 4];
                const float4 bq = *(const float4*)&b2_reg[G * CPAD + mt * 4];
                ac[j][0] = hr[mt*4+0]*csum - (c0*a0.x + c1*a1.x + c2*a2.x) + bq.x;
                ac[j][1] = hr[mt*4+1]*csum - (c0*a0.y + c1*a1.y + c2*a2.y) + bq.y;
                ac[j][2] = hr[mt*4+2]*csum - (c0*a0.z + c1*a1.z + c2*a2.z) + bq.z;
                ac[j][3] = hr[mt*4+3]*csum - (c0*a0.w + c1*a1.w + c2*a2.w) + bq.w;
            }
#pragma unroll
            for (int kk = 0; kk < 4; ++kk) {
                const int s = 8 + pass * 4 + kk;
                PIPE_SYNC();
                STAGE(CHB((s + 3) & 15), ((s + 3) & 3) * 1024);
                const int cb = (s & 3) * 1024;
#pragma unroll
                for (int ks2 = 0; ks2 < 2; ++ks2) {
                    const int ks = kk * 2 + ks2;
                    u32x4 thi = {tph[4*ks+0], tph[4*ks+1], tph[4*ks+2], tph[4*ks+3]};
                    const short8 Bh = __builtin_bit_cast(short8, thi);
#pragma unroll
                    for (int j = 0; j < 8; ++j) {
                        const short8 Ah = __builtin_bit_cast(short8,
                            wf[cb + ks2*512 + j*64 + lane]);
                        ac[j] = __builtin_amdgcn_mfma_f32_16x16x32_bf16(Ah, Bh, ac[j], 0, 0, 0);
                    }
                }
            }
#pragma unroll
            for (int j = 0; j < 8; ++j) {
                const int mt = pass * 8 + j;
                hr[mt*4+0] = ac[j][0]; hr[mt*4+1] = ac[j][1];
                hr[mt*4+2] = ac[j][2]; hr[mt*4+3] = ac[j][3];
            }
        }

        // ---------- norm clip (in regs) ----------
        {
            float ss = 0.0f;
#pragma unroll
            for (int s = 0; s < 64; ++s) ss += hr[s] * hr[s];
            ss += __shfl_xor(ss, 16);
            ss += __shfl_xor(ss, 32);
            const float n = sqrtf(ss);
            const float sc = (n > 10.0f) ? (10.0f / (n + 1e-8f)) : 1.0f;
#pragma unroll
            for (int s = 0; s < 64; ++s) hr[s] *= sc;
        }
    }

    // ---------- store h_final ----------
#pragma unroll
    for (int mt = 0; mt < 16; ++mt) {
        float4 v;
        v.x = hr[mt*4+0]; v.y = hr[mt*4+1]; v.z = hr[mt*4+2]; v.w = hr[mt*4+3];
        *(float4*)&out_h[(size_t)bglob * DIMX + 16 * mt + 4 * G] = v;
    }
}

extern "C" void kernel_launch(void* const* d_in, const int* in_sizes, int n_in,
                              void* d_out, int out_size, void* d_ws, size_t ws_size,
                              hipStream_t stream) {
    const float* h0      = (const float*)d_in[0];
    const float* W1      = (const float*)d_in[1];
    const float* b1      = (const float*)d_in[2];
    const float* W2      = (const float*)d_in[3];
    const float* b2      = (const float*)d_in[4];
    const float* anchors = (const float*)d_in[5];
    const int B = in_sizes[0] / DIMX;

    float* out_h     = (float*)d_out;
    float* out_align = out_h + (long long)B * DIMX;
    float* out_div   = out_align + (long long)NL * B * 3;
    float* out_tens  = out_div   + (long long)NL * B * 3;

    u32x4* ws = (u32x4*)d_ws;   // 256 KiB

    hipLaunchKernelGGL(wsplit, dim3(64), dim3(256), 0, stream, W1, W2, ws);
    hipLaunchKernelGGL(collapse_mfma16, dim3(B / 128), dim3(512), 0, stream,
                       h0, b1, b2, anchors, ws,
                       out_h, out_align, out_div, out_tens, B);
}